// Round 7
// baseline (4022.549 us; speedup 1.0000x reference)
//
#include <hip/hip_runtime.h>

#define BATCH 2048
#define TSEQ  64
#define DIN   512
#define HID   1024
#define CIN   1536   // DIN + HID

#define XKB   (DIN / 32)    // 16  k32-blocks in x
#define HKB   (HID / 32)    // 32  k32-blocks in h
#define WKB   (CIN / 32)    // 48  k32-blocks in weights
#define NMB   (BATCH / 16)  // 128 m-blocks of 16 rows
#define NNB   (HID / 16)    // 64  n-blocks of 16 cols

// fragment = [64 lanes][8 bf16] = 512 elems = 1 KB
// A-frag(mb,kb): elem(lane,j) = A[mb*16 + (lane&15)][kb*32 + (lane>>4)*8 + j]   (m120-verified)
// B-frag(nb,kb): elem(lane,j) = W[nb*16 + (lane&15)][kb*32 + (lane>>4)*8 + j]   (R1-R6-proven)

typedef __attribute__((ext_vector_type(8))) short bf16x8;
typedef __attribute__((ext_vector_type(4))) float f32x4;
typedef __attribute__((ext_vector_type(4))) float fvec4;
typedef __attribute__((ext_vector_type(4))) unsigned int uvec4;

__device__ __forceinline__ unsigned short f2bf(float f) {
    unsigned int u = __float_as_uint(f);
    u += 0x7fffu + ((u >> 16) & 1u);
    return (unsigned short)(u >> 16);
}
__device__ __forceinline__ float bf2f(unsigned short u) {
    return __uint_as_float(((unsigned int)u) << 16);
}
__device__ __forceinline__ uvec4 pack8(fvec4 a, fvec4 b) {
    uvec4 o;
    o.x = (unsigned)f2bf(a.x) | ((unsigned)f2bf(a.y) << 16);
    o.y = (unsigned)f2bf(a.z) | ((unsigned)f2bf(a.w) << 16);
    o.z = (unsigned)f2bf(b.x) | ((unsigned)f2bf(b.y) << 16);
    o.w = (unsigned)f2bf(b.z) | ((unsigned)f2bf(b.w) << 16);
    return o;
}

// ---- shuffle weights fp32 [HID][CIN] -> bf16 B-frags Wsh[mat][nb][kb] ----
// one wave per frag; wave reads 16 rows x 128 B (fully consumed lines)
__global__ __launch_bounds__(256) void shuffle_w(const float* __restrict__ Wf,
                                                 const float* __restrict__ Wg,
                                                 const float* __restrict__ Wh,
                                                 unsigned short* __restrict__ Wsh) {
    int fg   = blockIdx.x * 4 + (threadIdx.x >> 6);   // 0 .. 3*64*48-1
    int lane = threadIdx.x & 63;
    int mat  = fg / (NNB * WKB);
    int rem  = fg % (NNB * WKB);
    int nb = rem / WKB, kb = rem % WKB;
    const float* W = (mat == 0) ? Wf : ((mat == 1) ? Wg : Wh);
    const float* src = W + (size_t)(nb * 16 + (lane & 15)) * CIN + kb * 32 + (lane >> 4) * 8;
    fvec4 a = *(const fvec4*)src;
    fvec4 b = *(const fvec4*)(src + 4);
    *(uvec4*)(Wsh + (size_t)fg * 512 + lane * 8) = pack8(a, b);
}

// ---- shuffle x fp32 [B][T][D] -> bf16 A-frags xs[t][kb][mb] ----
__global__ __launch_bounds__(256) void shuffle_x(const float* __restrict__ x,
                                                 unsigned short* __restrict__ xs) {
    int fg   = blockIdx.x * 4 + (threadIdx.x >> 6);   // 0 .. 64*16*128-1
    int lane = threadIdx.x & 63;
    int t   = fg / (XKB * NMB);
    int rem = fg % (XKB * NMB);
    int kb = rem / NMB, mb = rem % NMB;
    int m = mb * 16 + (lane & 15);
    int c = kb * 32 + (lane >> 4) * 8;
    const float* src = x + ((size_t)m * TSEQ + t) * DIN + c;
    fvec4 a = *(const fvec4*)src;
    fvec4 b = *(const fvec4*)(src + 4);
    *(uvec4*)(xs + (size_t)fg * 512 + lane * 8) = pack8(a, b);
}

// ---- one recurrence step: barrier-free all-register fused 3xGEMM + gate ----
// grid 256 = 1 block/CU; block = 4 waves stacked in M: 256 rows x 32 cols.
// K-loop: 10 coalesced 1KB frag loads + 24 MFMA per k32, NO __syncthreads ->
// compiler pipelines loads with vmcnt(N) (AITER pattern). B shared by all
// 4 waves -> L1 dedupe; n-affinity keeps 1.18 MB weight slice per-XCD L2.
__global__ __launch_bounds__(256, 1) void step_kernel(
    const unsigned short* __restrict__ xs,     // A-frags [t][kb<16][mb]
    const unsigned short* __restrict__ Wsh,    // B-frags [mat][nb][kb]
    const float* __restrict__ bfv,
    const float* __restrict__ bgv,
    const float* __restrict__ bhv,
    const unsigned short* __restrict__ hin,    // A-frags [kb<32][mb]
    unsigned short* __restrict__ hout,         // A-frags [kb<32][mb]
    int t)
{
    const int tid  = threadIdx.x;
    const int bid  = blockIdx.x;
    const int n_tile = ((bid & 7) << 2) | ((bid >> 3) & 3);   // 0..31 (XCD n-affinity)
    const int mq     = bid >> 5;                              // 0..7
    const int lane = tid & 63;
    const int wave = tid >> 6;
    const int n0  = n_tile * 32;
    const int mb0 = mq * 16 + wave * 4;     // wave's 4 consecutive m-blocks

    f32x4 acc[3][4][2] = {};

    const int l8 = lane * 8;   // elem offset of this lane within a frag
    const unsigned short* ax = xs + ((size_t)t * XKB * NMB + mb0) * 512 + l8;
    const unsigned short* ah = hin + (size_t)mb0 * 512 + l8;
    const unsigned short* bp = Wsh + (size_t)(n_tile * 2) * WKB * 512 + l8;
    // strides (elems): A kb: NMB*512 = 65536, frag i: 512
    //                  B mat: 64*48*512 = 1572864, nt: 48*512 = 24576, kb: 512

    auto kstep = [&](const unsigned short* aptr, int kb) {
        bf16x8 a0 = *(const bf16x8*)(aptr);
        bf16x8 a1 = *(const bf16x8*)(aptr + 512);
        bf16x8 a2 = *(const bf16x8*)(aptr + 1024);
        bf16x8 a3 = *(const bf16x8*)(aptr + 1536);
        const unsigned short* bk = bp + (size_t)kb * 512;
        bf16x8 bq[3][2];
#pragma unroll
        for (int mat = 0; mat < 3; ++mat) {
            bq[mat][0] = *(const bf16x8*)(bk + (size_t)mat * 1572864);
            bq[mat][1] = *(const bf16x8*)(bk + (size_t)mat * 1572864 + 24576);
        }
#pragma unroll
        for (int mat = 0; mat < 3; ++mat) {
#pragma unroll
            for (int nt = 0; nt < 2; ++nt) {
                acc[mat][0][nt] = __builtin_amdgcn_mfma_f32_16x16x32_bf16(a0, bq[mat][nt], acc[mat][0][nt], 0, 0, 0);
                acc[mat][1][nt] = __builtin_amdgcn_mfma_f32_16x16x32_bf16(a1, bq[mat][nt], acc[mat][1][nt], 0, 0, 0);
                acc[mat][2][nt] = __builtin_amdgcn_mfma_f32_16x16x32_bf16(a2, bq[mat][nt], acc[mat][2][nt], 0, 0, 0);
                acc[mat][3][nt] = __builtin_amdgcn_mfma_f32_16x16x32_bf16(a3, bq[mat][nt], acc[mat][3][nt], 0, 0, 0);
            }
        }
    };

#pragma unroll 4
    for (int kb = 0; kb < XKB; ++kb) kstep(ax + (size_t)kb * 65536, kb);
#pragma unroll 4
    for (int kb = 0; kb < HKB; ++kb) kstep(ah + (size_t)kb * 65536, XKB + kb);

    // ---- epilogue: gate, then write h_out in A-frag order via LDS transpose ----
    float biasF[2], biasG[2], biasH[2];
#pragma unroll
    for (int nt = 0; nt < 2; ++nt) {
        int cg = n0 + nt * 16 + (lane & 15);
        biasF[nt] = bfv[cg];
        biasG[nt] = bgv[cg];
        biasH[nt] = bhv[cg];
    }

    __shared__ __align__(16) unsigned short sh[16 * 512];   // 16 KB: block's 16 mb-frags

    // C/D layout (16x16x32): col = lane&15, row = (lane>>4)*4 + r   [m89-verified]
    // target A-frag elem: lane' = (m&15) + 16*((c>>3)&3), j' = c&7
#pragma unroll
    for (int i = 0; i < 4; ++i) {
#pragma unroll
        for (int nt = 0; nt < 2; ++nt) {
#pragma unroll
            for (int r = 0; r < 4; ++r) {
                float f  = acc[0][i][nt][r] + biasF[nt];
                float g  = acc[1][i][nt][r] + biasG[nt];
                float hh = acc[2][i][nt][r] + biasH[nt];
                float gate = 1.0f / (1.0f + __expf(f));   // sigmoid(-f)
                float nh = hh + gate * (g - hh);
                int addr = (wave * 4 + i) * 512 + ((lane >> 4) * 4 + r) * 8
                         + (nt * 2 + ((lane >> 3) & 1)) * 128 + (lane & 7);
                sh[addr] = f2bf(nh);
            }
        }
    }
    __syncthreads();

    // writer: thread -> 32 elems (64 B) of one frag, NT-stored coalesced
    {
        int f   = tid >> 4;
        int off = (tid & 15) * 32;
        const unsigned short* s = sh + f * 512 + off;
        unsigned short* d = hout + ((size_t)(n_tile * NMB) + mq * 16 + f) * 512 + off;
#pragma unroll
        for (int q = 0; q < 4; ++q)
            __builtin_nontemporal_store(*(const uvec4*)(s + q * 8), (uvec4*)(d + q * 8));
    }
}

// ---- final FC: out[2048][2] = h @ Wfc^T + bfc (h in A-frag layout) ----
__global__ __launch_bounds__(256) void fc_kernel(const unsigned short* __restrict__ h,
                                                 const float* __restrict__ Wfc,
                                                 const float* __restrict__ bfc,
                                                 float* __restrict__ out) {
    int m   = blockIdx.x;
    int tid = threadIdx.x;
    // c = tid*4: h elem offset in frag layout
    size_t hoff = ((size_t)(tid >> 3) * NMB + (m >> 4)) * 512
                + ((m & 15) + 16 * ((tid >> 1) & 3)) * 8 + (tid & 1) * 4;
    ushort4 hv = *(const ushort4*)(h + hoff);
    float h0 = bf2f(hv.x), h1 = bf2f(hv.y), h2 = bf2f(hv.z), h3 = bf2f(hv.w);
    float4 w0 = *(const float4*)(Wfc + tid * 4);
    float4 w1 = *(const float4*)(Wfc + HID + tid * 4);
    float a0 = h0 * w0.x + h1 * w0.y + h2 * w0.z + h3 * w0.w;
    float a1 = h0 * w1.x + h1 * w1.y + h2 * w1.z + h3 * w1.w;
#pragma unroll
    for (int off = 32; off > 0; off >>= 1) {
        a0 += __shfl_down(a0, off);
        a1 += __shfl_down(a1, off);
    }
    __shared__ float red[2][4];
    if ((tid & 63) == 0) { red[0][tid >> 6] = a0; red[1][tid >> 6] = a1; }
    __syncthreads();
    if (tid == 0) out[(size_t)m * 2 + 0] = red[0][0] + red[0][1] + red[0][2] + red[0][3] + bfc[0];
    if (tid == 1) out[(size_t)m * 2 + 1] = red[1][0] + red[1][1] + red[1][2] + red[1][3] + bfc[1];
}

extern "C" void kernel_launch(void* const* d_in, const int* in_sizes, int n_in,
                              void* d_out, int out_size, void* d_ws, size_t ws_size,
                              hipStream_t stream) {
    const float* x   = (const float*)d_in[0];
    const float* Wf  = (const float*)d_in[1];
    const float* bfv = (const float*)d_in[2];
    const float* Wg  = (const float*)d_in[3];
    const float* bgv = (const float*)d_in[4];
    const float* Wh  = (const float*)d_in[5];
    const float* bhv = (const float*)d_in[6];
    const float* Wfc = (const float*)d_in[7];
    const float* bfc = (const float*)d_in[8];
    float* out = (float*)d_out;

    char* ws = (char*)d_ws;
    unsigned short* Wsh = (unsigned short*)ws;                       // 3*64*48 KB = 9.4 MB
    size_t wsh_bytes = (size_t)3 * NNB * WKB * 1024;
    size_t h_bytes   = (size_t)HKB * NMB * 1024;                     // 4 MB
    unsigned short* h0 = (unsigned short*)(ws + wsh_bytes);
    unsigned short* h1 = (unsigned short*)(ws + wsh_bytes + h_bytes);
    unsigned short* xs = (unsigned short*)(ws + wsh_bytes + 2 * h_bytes);  // 128 MB
    // ws use ~146 MB (harness ws ~1 GiB)

    shuffle_w<<<(3 * NNB * WKB) / 4, 256, 0, stream>>>(Wf, Wg, Wh, Wsh);
    shuffle_x<<<(TSEQ * XKB * NMB) / 4, 256, 0, stream>>>(x, xs);
    (void)hipMemsetAsync(h0, 0, h_bytes, stream);                    // h_0 = 0 (capturable)

    unsigned short* bufs[2] = {h0, h1};
    for (int t = 0; t < TSEQ; ++t) {
        step_kernel<<<256, 256, 0, stream>>>(xs, Wsh, bfv, bgv, bhv,
                                             bufs[t & 1], bufs[(t + 1) & 1], t);
    }
    // after 64 steps, final h is in bufs[0]
    fc_kernel<<<BATCH, 256, 0, stream>>>(h0, Wfc, bfc, out);
}